// Round 3
// baseline (188.140 us; speedup 1.0000x reference)
//
#include <hip/hip_runtime.h>
#include <hip/hip_bf16.h>

#define CIN   256
#define COUT  256
#define HH    56
#define WW    56
#define NB    32
#define KTOT  2304            // 3*3*256
#define MTOT  (NB * HH * WW)  // 100352

// ---- main (pipelined) kernel geometry ----
#define BM 128
#define BN 256
#define BK 32
#define NTHREADS 256
#define NSTEPS (KTOT / BK)    // 72 = 8 cin-chunks(32) * 9 taps

#define BT_BYTES  ((size_t)COUT * KTOT * 2)   // 1,179,648
#define XB_OFF    BT_BYTES
#define XB_BYTES  ((size_t)MTOT * CIN * 2)    // 51,380,224
#define ZB_OFF    (XB_OFF + XB_BYTES)
#define WS_NEEDED (ZB_OFF + 64)

typedef __attribute__((ext_vector_type(4))) float  f32x4;
typedef __attribute__((ext_vector_type(8))) __bf16 bf16x8;

__device__ __forceinline__ void gload_lds16(const void* g, void* l) {
    __builtin_amdgcn_global_load_lds(
        (const __attribute__((address_space(1))) void*)g,
        (__attribute__((address_space(3))) void*)l,
        16, 0, 0);
}

// ---- x fp32 -> bf16 cast (and zero-page init) ----
__global__ void xcast_kernel(const float* __restrict__ x, __bf16* __restrict__ xb,
                             float* __restrict__ zbuf) {
    const size_t total = (size_t)MTOT * CIN / 8;
    size_t idx = (size_t)blockIdx.x * blockDim.x + threadIdx.x;
    const size_t stride = (size_t)gridDim.x * blockDim.x;
    for (size_t g = idx; g < total; g += stride) {
        f32x4 v0 = ((const f32x4*)x)[2 * g];
        f32x4 v1 = ((const f32x4*)x)[2 * g + 1];
        bf16x8 o;
        o[0] = (__bf16)v0[0]; o[1] = (__bf16)v0[1];
        o[2] = (__bf16)v0[2]; o[3] = (__bf16)v0[3];
        o[4] = (__bf16)v1[0]; o[5] = (__bf16)v1[1];
        o[6] = (__bf16)v1[2]; o[7] = (__bf16)v1[3];
        ((bf16x8*)xb)[g] = o;
    }
    if (blockIdx.x == 0 && threadIdx.x < 16) zbuf[threadIdx.x] = 0.f;
}

// ---- binarize W -> bt[cout][ks*32 + swizzled ci] bf16 {+-1,0}; BK=32 layout ----
// ks = cin_chunk32 * 9 + tap (taps innermost). Pre-swizzled: ci ^ ((co&3)<<3).
__global__ void binarize_w_kernel(const float* __restrict__ W,
                                  unsigned short* __restrict__ bt) {
    int k  = blockIdx.x;    // tap*256 + cin
    int co = threadIdx.x;
    int tap = k >> 8, cin = k & 255;
    int c2 = cin >> 5, ci = cin & 31;
    int ks = c2 * 9 + tap;
    float w = W[(size_t)k * COUT + co];
    unsigned short s = (w > 0.f) ? 0x3F80u : ((w < 0.f) ? 0xBF80u : 0u);
    bt[(size_t)co * KTOT + ks * 32 + (ci ^ ((co & 3) << 3))] = s;
}

// ---- main conv: 128x256 tile, 4 waves (1M x 4N, 128x64/wave), BK=32,
//      double-buffered LDS + counted-vmcnt pipeline ----
__global__ __launch_bounds__(NTHREADS, 2)
void bconv_kernel(const __bf16* __restrict__ xb,
                  const unsigned short* __restrict__ bt,
                  const float* __restrict__ bias,
                  float* __restrict__ out,
                  const char* __restrict__ zb) {
    __shared__ __bf16 Al[2][BM][BK];   // 2 x 8 KB
    __shared__ __bf16 Bl[2][BN][BK];   // 2 x 16 KB   (total 48 KB)

    const int tid  = threadIdx.x;
    const int lane = tid & 63;
    const int wid  = tid >> 6;

    // XCD-aware bijective swizzle: 784 = 8 * 98
    const int bid = blockIdx.x;
    const int swz = (bid & 7) * (MTOT / BM / 8) + (bid >> 3);
    const int m_base = swz * BM;

    const int wn = wid * 64;   // wave's N-base; every wave covers all 128 M rows

    // B staging: 4 gload_lds/thread; load j covers rows j*64 + wid*16 + (lane>>2)
    const int    rB  = wid * 16 + (lane >> 2);
    const size_t bB0 = (size_t)rB * (KTOT * 2) + (size_t)(lane & 3) * 16;

    // A staging: 2 gload_lds/thread; load i covers rows i*64 + wid*16 + (lane>>2)
    const int chunk = (lane & 3) ^ ((lane >> 2) & 3);   // source pre-swizzle
    int aH[2], aW[2];
    long aOff[2];
#pragma unroll
    for (int i = 0; i < 2; ++i) {
        int r = i * 64 + wid * 16 + (lane >> 2);
        int flat = m_base + r;
        aW[i] = flat % WW;
        aH[i] = (flat / WW) % HH;
        aOff[i] = (long)flat * (CIN * 2) + chunk * 16;
    }

    f32x4 acc[8][4];
#pragma unroll
    for (int i = 0; i < 8; ++i)
#pragma unroll
        for (int j = 0; j < 4; ++j)
            acc[i][j] = (f32x4){0.f, 0.f, 0.f, 0.f};

    const char* xbb = (const char*)xb;
    const char* btb = (const char*)bt;

    auto STAGE = [&](int ks, int buf) {
#pragma unroll
        for (int j = 0; j < 4; ++j)
            gload_lds16(btb + bB0 + (size_t)j * 64 * (KTOT * 2) + (size_t)ks * 64,
                        &Bl[buf][j * 64 + wid * 16][0]);
        const int c2  = ks / 9;
        const int tap = ks - c2 * 9;
        const int dh  = tap / 3 - 1;
        const int dw  = tap % 3 - 1;
        const int doff = dh * WW + dw;
#pragma unroll
        for (int i = 0; i < 2; ++i) {
            int ih = aH[i] + dh, iw = aW[i] + dw;
            bool valid = ((unsigned)ih < (unsigned)HH) && ((unsigned)iw < (unsigned)WW);
            const char* g = valid ? (xbb + aOff[i] + (long)doff * (CIN * 2) + c2 * 64)
                                  : (const char*)zb;
            gload_lds16(g, &Al[buf][i * 64 + wid * 16][0]);
        }
    };

    // prologue: stage step 0 into buf 0 (6 loads in flight)
    STAGE(0, 0);

    const int rsel = lane & 15;
    const int cb   = (lane >> 4) * 16;        // logical 16B chunk within 64-B row
    const int sw   = (lane & 3) << 4;         // read-side XOR swizzle (row&3 == lane&3)

    for (int ks = 0; ks < NSTEPS; ++ks) {
        const int cur = ks & 1;
        if (ks + 1 < NSTEPS) {
            STAGE(ks + 1, cur ^ 1);                              // prefetch next step
            asm volatile("s_waitcnt vmcnt(6)" ::: "memory");     // drain only cur's 6 loads
        } else {
            asm volatile("s_waitcnt vmcnt(0)" ::: "memory");
        }
        __builtin_amdgcn_s_barrier();            // all waves' cur staging landed
        asm volatile("" ::: "memory");

        const char* Ab = (const char*)&Al[cur][0][0];
        const char* Bb = (const char*)&Bl[cur][0][0];
        bf16x8 af[8], bfr[4];
#pragma unroll
        for (int ni = 0; ni < 4; ++ni)
            bfr[ni] = *(const bf16x8*)(Bb + (wn + ni * 16 + rsel) * (BK * 2) + (cb ^ sw));
#pragma unroll
        for (int mi = 0; mi < 8; ++mi)
            af[mi] = *(const bf16x8*)(Ab + (mi * 16 + rsel) * (BK * 2) + (cb ^ sw));
#pragma unroll
        for (int mi = 0; mi < 8; ++mi)
#pragma unroll
            for (int ni = 0; ni < 4; ++ni)
                acc[mi][ni] = __builtin_amdgcn_mfma_f32_16x16x32_bf16(
                    af[mi], bfr[ni], acc[mi][ni], 0, 0, 0);

        asm volatile("s_waitcnt lgkmcnt(0)" ::: "memory");   // my reads of cur done
        __builtin_amdgcn_s_barrier();            // safe to overwrite cur next iter
        asm volatile("" ::: "memory");
    }

    // --- epilogue: bias + ReLU.  C/D layout: col = lane&15, row = (lane>>4)*4 + j
    const int col_l  = lane & 15;
    const int row_g4 = (lane >> 4) * 4;
#pragma unroll
    for (int ni = 0; ni < 4; ++ni) {
        const int cout = wn + ni * 16 + col_l;
        const float bv = bias[cout];
#pragma unroll
        for (int mi = 0; mi < 8; ++mi) {
            const int row = m_base + mi * 16 + row_g4;
#pragma unroll
            for (int j = 0; j < 4; ++j) {
                float v = acc[mi][ni][j] + bv;
                out[(size_t)(row + j) * COUT + cout] = v > 0.f ? v : 0.f;
            }
        }
    }
}

// ================= fallback path (ws too small): round-2 kernel, verbatim ====
__global__ void binarize_w_old_kernel(const float* __restrict__ W,
                                      unsigned short* __restrict__ bt) {
    int k  = blockIdx.x;    // tap*256 + cin
    int co = threadIdx.x;
    int tap = k >> 8, cin = k & 255;
    int c = cin >> 6, ci = cin & 63;
    int ks = c * 9 + tap;
    float w = W[(size_t)k * COUT + co];
    unsigned short s = (w > 0.f) ? 0x3F80u : ((w < 0.f) ? 0xBF80u : 0u);
    bt[(size_t)co * KTOT + ks * 64 + (ci ^ ((co & 7) << 3))] = s;
}

__global__ __launch_bounds__(512, 4)
void bconv_old_kernel(const float* __restrict__ x,
                      const unsigned short* __restrict__ bt,
                      const float* __restrict__ bias,
                      float* __restrict__ out) {
    __shared__ __bf16 Al[128][64];
    __shared__ __bf16 Bl[256][64];

    const int tid  = threadIdx.x;
    const int lane = tid & 63;
    const int wid  = tid >> 6;

    const int bid = blockIdx.x;
    const int swz = (bid & 7) * (MTOT / 128 / 8) + (bid >> 3);
    const int m_base = swz * 128;

    const int wm = (wid & 1) * 64;
    const int wn = (wid >> 1) * 64;

    const int  rB0 = wid * 32 + (lane >> 3);
    const long bB0 = (long)rB0 * (KTOT * 2) + (lane & 7) * 16;

    int aH[2], aW[2], aOff[2];
#pragma unroll
    for (int i = 0; i < 2; ++i) {
        int r = i * 64 + (tid >> 3);
        int flat = m_base + r;
        aW[i] = flat % WW;
        aH[i] = (flat / WW) % HH;
        aOff[i] = flat * (CIN * 4);
    }

    f32x4 acc[4][4];
#pragma unroll
    for (int i = 0; i < 4; ++i)
#pragma unroll
        for (int j = 0; j < 4; ++j)
            acc[i][j] = (f32x4){0.f, 0.f, 0.f, 0.f};

    const char* xfb = (const char*)x;
    const char* btb = (const char*)bt;

    for (int ks = 0; ks < 36; ++ks) {
        const int c    = ks / 9;
        const int tap  = ks % 9;
        const int dh   = tap / 3 - 1;
        const int dw   = tap % 3 - 1;
        const int doff = dh * WW + dw;

        __syncthreads();

#pragma unroll
        for (int i = 0; i < 4; ++i) {
            const char* g = btb + bB0 + (long)i * 8 * (KTOT * 2) + ks * 128;
            gload_lds16(g, &Bl[wid * 32 + i * 8][0]);
        }

        const int cg = tid & 7;
#pragma unroll
        for (int i = 0; i < 2; ++i) {
            int ih = aH[i] + dh, iw = aW[i] + dw;
            f32x4 v0 = (f32x4){0.f, 0.f, 0.f, 0.f};
            f32x4 v1 = (f32x4){0.f, 0.f, 0.f, 0.f};
            if (((unsigned)ih < (unsigned)HH) && ((unsigned)iw < (unsigned)WW)) {
                const float* gp = (const float*)(xfb +
                    (long)(aOff[i] + doff * (CIN * 4) + c * 256 + cg * 32));
                v0 = ((const f32x4*)gp)[0];
                v1 = ((const f32x4*)gp)[1];
            }
            bf16x8 o;
            o[0] = (__bf16)v0[0]; o[1] = (__bf16)v0[1];
            o[2] = (__bf16)v0[2]; o[3] = (__bf16)v0[3];
            o[4] = (__bf16)v1[0]; o[5] = (__bf16)v1[1];
            o[6] = (__bf16)v1[2]; o[7] = (__bf16)v1[3];
            int r = i * 64 + (tid >> 3);
            *(bf16x8*)((char*)&Al[0][0] + r * 128 + ((cg * 16) ^ ((r & 7) << 4))) = o;
        }

        __syncthreads();

        const char* Ab = (const char*)&Al[0][0];
        const char* Bb = (const char*)&Bl[0][0];
        const int swzr = (lane & 7) << 4;
        const int rsel = lane & 15;
        const int csel = (lane >> 4) * 16;
#pragma unroll
        for (int kk = 0; kk < 2; ++kk) {
            const int colb = kk * 64 + csel;
            bf16x8 af[4], bfr[4];
#pragma unroll
            for (int mi = 0; mi < 4; ++mi)
                af[mi] = *(const bf16x8*)(Ab + (wm + mi * 16 + rsel) * 128 + (colb ^ swzr));
#pragma unroll
            for (int ni = 0; ni < 4; ++ni)
                bfr[ni] = *(const bf16x8*)(Bb + (wn + ni * 16 + rsel) * 128 + (colb ^ swzr));
#pragma unroll
            for (int mi = 0; mi < 4; ++mi)
#pragma unroll
                for (int ni = 0; ni < 4; ++ni)
                    acc[mi][ni] = __builtin_amdgcn_mfma_f32_16x16x32_bf16(
                        af[mi], bfr[ni], acc[mi][ni], 0, 0, 0);
        }
    }

    const int col_l  = lane & 15;
    const int row_g4 = (lane >> 4) * 4;
#pragma unroll
    for (int ni = 0; ni < 4; ++ni) {
        const int cout = wn + ni * 16 + col_l;
        const float bv = bias[cout];
#pragma unroll
        for (int mi = 0; mi < 4; ++mi) {
            const int row = m_base + wm + mi * 16 + row_g4;
#pragma unroll
            for (int j = 0; j < 4; ++j) {
                float v = acc[mi][ni][j] + bv;
                out[(size_t)(row + j) * COUT + cout] = v > 0.f ? v : 0.f;
            }
        }
    }
}

extern "C" void kernel_launch(void* const* d_in, const int* in_sizes, int n_in,
                              void* d_out, int out_size, void* d_ws, size_t ws_size,
                              hipStream_t stream) {
    const float* x = (const float*)d_in[0];   // (32,56,56,256) fp32
    const float* W = (const float*)d_in[1];   // (3,3,256,256) fp32
    const float* b = (const float*)d_in[2];   // (256,) fp32
    float* out = (float*)d_out;

    char* ws = (char*)d_ws;
    unsigned short* bt = (unsigned short*)ws;
    __bf16* xb   = (__bf16*)(ws + XB_OFF);
    float*  zbuf = (float*)(ws + ZB_OFF);

    if (ws_size >= WS_NEEDED) {
        binarize_w_kernel<<<dim3(KTOT), dim3(COUT), 0, stream>>>(W, bt);
        xcast_kernel<<<dim3(2048), dim3(256), 0, stream>>>(x, xb, zbuf);
        bconv_kernel<<<dim3(MTOT / BM), dim3(NTHREADS), 0, stream>>>(
            xb, bt, b, out, (const char*)zbuf);
    } else {
        binarize_w_old_kernel<<<dim3(KTOT), dim3(COUT), 0, stream>>>(W, bt);
        bconv_old_kernel<<<dim3(MTOT / 128), dim3(512), 0, stream>>>(x, bt, b, out);
    }
}

// Round 4
// 182.377 us; speedup vs baseline: 1.0316x; 1.0316x over previous
//
#include <hip/hip_runtime.h>
#include <hip/hip_bf16.h>

#define CIN   256
#define COUT  256
#define HH    56
#define WW    56
#define NB    32
#define KTOT  2304            // 3*3*256
#define MTOT  (NB * HH * WW)  // 100352

// ---- main (pipelined) kernel geometry ----
#define BM 128
#define BN 256
#define BK 32
#define NTHREADS 256          // 4 waves; wave tile 128x64
#define NSTEPS (KTOT / BK)    // 72 = 8 cin-chunks(32) * 9 taps

#define BT_BYTES  ((size_t)COUT * KTOT * 2)   // 1,179,648
#define XB_OFF    BT_BYTES
#define XB_BYTES  ((size_t)MTOT * CIN * 2)    // 51,380,224
#define ZB_OFF    (XB_OFF + XB_BYTES)
#define WS_NEEDED (ZB_OFF + 64)

typedef __attribute__((ext_vector_type(4))) float  f32x4;
typedef __attribute__((ext_vector_type(8))) __bf16 bf16x8;

__device__ __forceinline__ void gload_lds16(const void* g, void* l) {
    __builtin_amdgcn_global_load_lds(
        (const __attribute__((address_space(1))) void*)g,
        (__attribute__((address_space(3))) void*)l,
        16, 0, 0);
}

// ---- x fp32 -> bf16 cast (and zero-page init) ----
__global__ void xcast_kernel(const float* __restrict__ x, __bf16* __restrict__ xb,
                             float* __restrict__ zbuf) {
    const size_t total = (size_t)MTOT * CIN / 8;
    size_t idx = (size_t)blockIdx.x * blockDim.x + threadIdx.x;
    const size_t stride = (size_t)gridDim.x * blockDim.x;
    for (size_t g = idx; g < total; g += stride) {
        f32x4 v0 = ((const f32x4*)x)[2 * g];
        f32x4 v1 = ((const f32x4*)x)[2 * g + 1];
        bf16x8 o;
        o[0] = (__bf16)v0[0]; o[1] = (__bf16)v0[1];
        o[2] = (__bf16)v0[2]; o[3] = (__bf16)v0[3];
        o[4] = (__bf16)v1[0]; o[5] = (__bf16)v1[1];
        o[6] = (__bf16)v1[2]; o[7] = (__bf16)v1[3];
        ((bf16x8*)xb)[g] = o;
    }
    if (blockIdx.x == 0 && threadIdx.x < 16) zbuf[threadIdx.x] = 0.f;
}

// ---- binarize W -> bt[cout][ks*32 + swz(ci)] bf16 {+-1,0}; BK=32 layout ----
// ks = cin_chunk32 * 9 + tap (taps innermost).
// Pre-swizzle for 64-B LDS rows: element ci stored at ci ^ (((co>>1)&3)<<3).
__global__ void binarize_w_kernel(const float* __restrict__ W,
                                  unsigned short* __restrict__ bt) {
    int k  = blockIdx.x;    // tap*256 + cin
    int co = threadIdx.x;
    int tap = k >> 8, cin = k & 255;
    int c2 = cin >> 5, ci = cin & 31;
    int ks = c2 * 9 + tap;
    float w = W[(size_t)k * COUT + co];
    unsigned short s = (w > 0.f) ? 0x3F80u : ((w < 0.f) ? 0xBF80u : 0u);
    bt[(size_t)co * KTOT + ks * 32 + (ci ^ (((co >> 1) & 3) << 3))] = s;
}

// ---- main conv: 128x256 tile, 4 waves (128x64 each), BK=32,
//      double-buffered LDS + counted-vmcnt pipeline, S(row)=(row>>1)&3 swizzle ----
__global__ __launch_bounds__(NTHREADS, 2)
void bconv_kernel(const __bf16* __restrict__ xb,
                  const unsigned short* __restrict__ bt,
                  const float* __restrict__ bias,
                  float* __restrict__ out,
                  const char* __restrict__ zb) {
    __shared__ __bf16 Al[2][BM][BK];   // 2 x 8 KB
    __shared__ __bf16 Bl[2][BN][BK];   // 2 x 16 KB   (total 48 KB)

    const int tid  = threadIdx.x;
    const int lane = tid & 63;
    const int wid  = tid >> 6;

    // XCD-aware bijective swizzle: 784 = 8 * 98
    const int bid = blockIdx.x;
    const int swz = (bid & 7) * (MTOT / BM / 8) + (bid >> 3);
    const int m_base = swz * BM;

    const int wn = wid * 64;   // wave's cout base; every wave covers all 128 M rows

    // --- B staging: 4 loads/thread; load j covers couts j*64 + wid*16 + (lane>>2) ---
    long bBase[4];
#pragma unroll
    for (int j = 0; j < 4; ++j) {
        int co = j * 64 + wid * 16 + (lane >> 2);
        bBase[j] = (long)co * (KTOT * 2) + (long)(lane & 3) * 16;
    }

    // --- A staging: 2 loads/thread; load i covers LDS rows wid*32 + i*16 + (lane>>2) ---
    // source pre-swizzle: S(row) = (row>>1)&3 = (lane>>3)&3 for this mapping
    const int schunk = (lane & 3) ^ ((lane >> 3) & 3);
    int aH[2], aW[2];
    long aBase[2];
#pragma unroll
    for (int i = 0; i < 2; ++i) {
        int r = wid * 32 + i * 16 + (lane >> 2);
        int flat = m_base + r;
        aW[i] = flat % WW;
        aH[i] = (flat / WW) % HH;
        aBase[i] = (long)flat * (CIN * 2) + schunk * 16;
    }

    f32x4 acc[8][4];
#pragma unroll
    for (int i = 0; i < 8; ++i)
#pragma unroll
        for (int j = 0; j < 4; ++j)
            acc[i][j] = (f32x4){0.f, 0.f, 0.f, 0.f};

    const char* xbb = (const char*)xb;
    const char* btb = (const char*)bt;

    auto STAGE = [&](int ks, int buf) {
#pragma unroll
        for (int j = 0; j < 4; ++j)
            gload_lds16(btb + bBase[j] + (long)ks * 64,
                        &Bl[buf][j * 64 + wid * 16][0]);
        const int c2  = ks / 9;
        const int tap = ks - c2 * 9;
        const int dh  = tap / 3 - 1;
        const int dw  = tap % 3 - 1;
        const long doff = (long)(dh * WW + dw) * (CIN * 2);
#pragma unroll
        for (int i = 0; i < 2; ++i) {
            int ih = aH[i] + dh, iw = aW[i] + dw;
            bool valid = ((unsigned)ih < (unsigned)HH) && ((unsigned)iw < (unsigned)WW);
            const char* g = valid ? (xbb + aBase[i] + doff + c2 * 64)
                                  : (const char*)zb;
            gload_lds16(g, &Al[buf][wid * 32 + i * 16][0]);
        }
    };

    // prologue: stage step 0 into buf 0 (6 loads in flight)
    STAGE(0, 0);

    // fragment-read geometry: row = frag*16 + (lane&15), chunk C = lane>>4,
    // read chunk slot = C ^ S(row), S(row) = ((lane&15)>>1)&3
    const int rsel = lane & 15;
    const int cbyte = ((lane >> 4) ^ ((rsel >> 1) & 3)) * 16;

    for (int ks = 0; ks < NSTEPS; ++ks) {
        const int cur = ks & 1;
        if (ks + 1 < NSTEPS) {
            STAGE(ks + 1, cur ^ 1);                              // prefetch next step
            asm volatile("s_waitcnt vmcnt(6)" ::: "memory");     // drain only cur's 6 loads
        } else {
            asm volatile("s_waitcnt vmcnt(0)" ::: "memory");
        }
        __builtin_amdgcn_s_barrier();            // all waves' cur staging landed
        asm volatile("" ::: "memory");

        const char* Ab = (const char*)&Al[cur][0][0];
        const char* Bb = (const char*)&Bl[cur][0][0];
        bf16x8 af[8], bfr[4];
#pragma unroll
        for (int ni = 0; ni < 4; ++ni)
            bfr[ni] = *(const bf16x8*)(Bb + (wn + ni * 16 + rsel) * (BK * 2) + cbyte);
#pragma unroll
        for (int mi = 0; mi < 8; ++mi)
            af[mi] = *(const bf16x8*)(Ab + (mi * 16 + rsel) * (BK * 2) + cbyte);

        __builtin_amdgcn_s_setprio(1);
#pragma unroll
        for (int mi = 0; mi < 8; ++mi)
#pragma unroll
            for (int ni = 0; ni < 4; ++ni)
                acc[mi][ni] = __builtin_amdgcn_mfma_f32_16x16x32_bf16(
                    af[mi], bfr[ni], acc[mi][ni], 0, 0, 0);
        __builtin_amdgcn_s_setprio(0);

        asm volatile("s_waitcnt lgkmcnt(0)" ::: "memory");   // my reads of cur done
        __builtin_amdgcn_s_barrier();            // safe to overwrite cur next iter
        asm volatile("" ::: "memory");
    }

    // --- epilogue: bias + ReLU.  C/D layout: col = lane&15, row = (lane>>4)*4 + j
    const int col_l  = lane & 15;
    const int row_g4 = (lane >> 4) * 4;
#pragma unroll
    for (int ni = 0; ni < 4; ++ni) {
        const int cout = wn + ni * 16 + col_l;
        const float bv = bias[cout];
#pragma unroll
        for (int mi = 0; mi < 8; ++mi) {
            const int row = m_base + mi * 16 + row_g4;
#pragma unroll
            for (int j = 0; j < 4; ++j) {
                float v = acc[mi][ni][j] + bv;
                out[(size_t)(row + j) * COUT + cout] = v > 0.f ? v : 0.f;
            }
        }
    }
}

// ================= fallback path (ws too small): round-2 fallback, verbatim ====
__global__ void binarize_w_old_kernel(const float* __restrict__ W,
                                      unsigned short* __restrict__ bt) {
    int k  = blockIdx.x;    // tap*256 + cin
    int co = threadIdx.x;
    int tap = k >> 8, cin = k & 255;
    int c = cin >> 6, ci = cin & 63;
    int ks = c * 9 + tap;
    float w = W[(size_t)k * COUT + co];
    unsigned short s = (w > 0.f) ? 0x3F80u : ((w < 0.f) ? 0xBF80u : 0u);
    bt[(size_t)co * KTOT + ks * 64 + (ci ^ ((co & 7) << 3))] = s;
}

__global__ __launch_bounds__(512, 4)
void bconv_old_kernel(const float* __restrict__ x,
                      const unsigned short* __restrict__ bt,
                      const float* __restrict__ bias,
                      float* __restrict__ out) {
    __shared__ __bf16 Al[128][64];
    __shared__ __bf16 Bl[256][64];

    const int tid  = threadIdx.x;
    const int lane = tid & 63;
    const int wid  = tid >> 6;

    const int bid = blockIdx.x;
    const int swz = (bid & 7) * (MTOT / 128 / 8) + (bid >> 3);
    const int m_base = swz * 128;

    const int wm = (wid & 1) * 64;
    const int wn = (wid >> 1) * 64;

    const int  rB0 = wid * 32 + (lane >> 3);
    const long bB0 = (long)rB0 * (KTOT * 2) + (lane & 7) * 16;

    int aH[2], aW[2], aOff[2];
#pragma unroll
    for (int i = 0; i < 2; ++i) {
        int r = i * 64 + (tid >> 3);
        int flat = m_base + r;
        aW[i] = flat % WW;
        aH[i] = (flat / WW) % HH;
        aOff[i] = flat * (CIN * 4);
    }

    f32x4 acc[4][4];
#pragma unroll
    for (int i = 0; i < 4; ++i)
#pragma unroll
        for (int j = 0; j < 4; ++j)
            acc[i][j] = (f32x4){0.f, 0.f, 0.f, 0.f};

    const char* xfb = (const char*)x;
    const char* btb = (const char*)bt;

    for (int ks = 0; ks < 36; ++ks) {
        const int c    = ks / 9;
        const int tap  = ks % 9;
        const int dh   = tap / 3 - 1;
        const int dw   = tap % 3 - 1;
        const int doff = dh * WW + dw;

        __syncthreads();

#pragma unroll
        for (int i = 0; i < 4; ++i) {
            const char* g = btb + bB0 + (long)i * 8 * (KTOT * 2) + ks * 128;
            gload_lds16(g, &Bl[wid * 32 + i * 8][0]);
        }

        const int cg = tid & 7;
#pragma unroll
        for (int i = 0; i < 2; ++i) {
            int ih = aH[i] + dh, iw = aW[i] + dw;
            f32x4 v0 = (f32x4){0.f, 0.f, 0.f, 0.f};
            f32x4 v1 = (f32x4){0.f, 0.f, 0.f, 0.f};
            if (((unsigned)ih < (unsigned)HH) && ((unsigned)iw < (unsigned)WW)) {
                const float* gp = (const float*)(xfb +
                    (long)(aOff[i] + doff * (CIN * 4) + c * 256 + cg * 32));
                v0 = ((const f32x4*)gp)[0];
                v1 = ((const f32x4*)gp)[1];
            }
            bf16x8 o;
            o[0] = (__bf16)v0[0]; o[1] = (__bf16)v0[1];
            o[2] = (__bf16)v0[2]; o[3] = (__bf16)v0[3];
            o[4] = (__bf16)v1[0]; o[5] = (__bf16)v1[1];
            o[6] = (__bf16)v1[2]; o[7] = (__bf16)v1[3];
            int r = i * 64 + (tid >> 3);
            *(bf16x8*)((char*)&Al[0][0] + r * 128 + ((cg * 16) ^ ((r & 7) << 4))) = o;
        }

        __syncthreads();

        const char* Ab = (const char*)&Al[0][0];
        const char* Bb = (const char*)&Bl[0][0];
        const int swzr = (lane & 7) << 4;
        const int rsel = lane & 15;
        const int csel = (lane >> 4) * 16;
#pragma unroll
        for (int kk = 0; kk < 2; ++kk) {
            const int colb = kk * 64 + csel;
            bf16x8 af[4], bfr[4];
#pragma unroll
            for (int mi = 0; mi < 4; ++mi)
                af[mi] = *(const bf16x8*)(Ab + (wm + mi * 16 + rsel) * 128 + (colb ^ swzr));
#pragma unroll
            for (int ni = 0; ni < 4; ++ni)
                bfr[ni] = *(const bf16x8*)(Bb + (wn + ni * 16 + rsel) * 128 + (colb ^ swzr));
#pragma unroll
            for (int mi = 0; mi < 4; ++mi)
#pragma unroll
                for (int ni = 0; ni < 4; ++ni)
                    acc[mi][ni] = __builtin_amdgcn_mfma_f32_16x16x32_bf16(
                        af[mi], bfr[ni], acc[mi][ni], 0, 0, 0);
        }
    }

    const int col_l  = lane & 15;
    const int row_g4 = (lane >> 4) * 4;
#pragma unroll
    for (int ni = 0; ni < 4; ++ni) {
        const int cout = wn + ni * 16 + col_l;
        const float bv = bias[cout];
#pragma unroll
        for (int mi = 0; mi < 4; ++mi) {
            const int row = m_base + wm + mi * 16 + row_g4;
#pragma unroll
            for (int j = 0; j < 4; ++j) {
                float v = acc[mi][ni][j] + bv;
                out[(size_t)(row + j) * COUT + cout] = v > 0.f ? v : 0.f;
            }
        }
    }
}

extern "C" void kernel_launch(void* const* d_in, const int* in_sizes, int n_in,
                              void* d_out, int out_size, void* d_ws, size_t ws_size,
                              hipStream_t stream) {
    const float* x = (const float*)d_in[0];   // (32,56,56,256) fp32
    const float* W = (const float*)d_in[1];   // (3,3,256,256) fp32
    const float* b = (const float*)d_in[2];   // (256,) fp32
    float* out = (float*)d_out;

    char* ws = (char*)d_ws;
    unsigned short* bt = (unsigned short*)ws;
    __bf16* xb   = (__bf16*)(ws + XB_OFF);
    float*  zbuf = (float*)(ws + ZB_OFF);

    if (ws_size >= WS_NEEDED) {
        binarize_w_kernel<<<dim3(KTOT), dim3(COUT), 0, stream>>>(W, bt);
        xcast_kernel<<<dim3(2048), dim3(256), 0, stream>>>(x, xb, zbuf);
        bconv_kernel<<<dim3(MTOT / BM), dim3(NTHREADS), 0, stream>>>(
            xb, bt, b, out, (const char*)zbuf);
    } else {
        binarize_w_old_kernel<<<dim3(KTOT), dim3(COUT), 0, stream>>>(W, bt);
        bconv_old_kernel<<<dim3(MTOT / 128), dim3(512), 0, stream>>>(x, bt, b, out);
    }
}

// Round 5
// 157.491 us; speedup vs baseline: 1.1946x; 1.1580x over previous
//
#include <hip/hip_runtime.h>
#include <hip/hip_bf16.h>

#define CIN   256
#define COUT  256
#define HH    56
#define WW    56
#define NB    32
#define KTOT  2304            // 3*3*256
#define MTOT  (NB * HH * WW)  // 100352

// ---- main kernel geometry: 128x256 tile, 8 waves (64x64 each), BK=32,
//      TRIPLE-buffered LDS, staging 2 tiles ahead, counted vmcnt ----
#define BM 128
#define BN 256
#define BK 32
#define NTHREADS 512
#define NSTEPS (KTOT / BK)        // 72 = 8 cin-chunks(32) * 9 taps
#define SLOT_ELEMS (BM * BK + BN * BK)   // 12288 elems = 24 KB per slot

#define BT_BYTES  ((size_t)COUT * KTOT * 2)   // 1,179,648
#define XB_OFF    BT_BYTES
#define XB_BYTES  ((size_t)MTOT * CIN * 2)    // 51,380,224
#define ZB_OFF    (XB_OFF + XB_BYTES)
#define WS_NEEDED (ZB_OFF + 64)

typedef __attribute__((ext_vector_type(4))) float  f32x4;
typedef __attribute__((ext_vector_type(8))) __bf16 bf16x8;

__device__ __forceinline__ void gload_lds16(const void* g, void* l) {
    __builtin_amdgcn_global_load_lds(
        (const __attribute__((address_space(1))) void*)g,
        (__attribute__((address_space(3))) void*)l,
        16, 0, 0);
}

// ---- x fp32 -> bf16 cast (and zero-page init) ----
__global__ void xcast_kernel(const float* __restrict__ x, __bf16* __restrict__ xb,
                             float* __restrict__ zbuf) {
    const size_t total = (size_t)MTOT * CIN / 8;
    size_t idx = (size_t)blockIdx.x * blockDim.x + threadIdx.x;
    const size_t stride = (size_t)gridDim.x * blockDim.x;
    for (size_t g = idx; g < total; g += stride) {
        f32x4 v0 = ((const f32x4*)x)[2 * g];
        f32x4 v1 = ((const f32x4*)x)[2 * g + 1];
        bf16x8 o;
        o[0] = (__bf16)v0[0]; o[1] = (__bf16)v0[1];
        o[2] = (__bf16)v0[2]; o[3] = (__bf16)v0[3];
        o[4] = (__bf16)v1[0]; o[5] = (__bf16)v1[1];
        o[6] = (__bf16)v1[2]; o[7] = (__bf16)v1[3];
        ((bf16x8*)xb)[g] = o;
    }
    if (blockIdx.x == 0 && threadIdx.x < 16) zbuf[threadIdx.x] = 0.f;
}

// ---- binarize W -> bt[cout][ks*32 + swz(ci)] bf16 {+-1,0}; BK=32 layout ----
// ks = cin_chunk32 * 9 + tap (taps innermost). Pre-swizzle: ci ^ (((co>>1)&3)<<3).
// (round-4 layout, proven 0 LDS bank conflicts)
__global__ void binarize_w_kernel(const float* __restrict__ W,
                                  unsigned short* __restrict__ bt) {
    int k  = blockIdx.x;    // tap*256 + cin
    int co = threadIdx.x;
    int tap = k >> 8, cin = k & 255;
    int c2 = cin >> 5, ci = cin & 31;
    int ks = c2 * 9 + tap;
    float w = W[(size_t)k * COUT + co];
    unsigned short s = (w > 0.f) ? 0x3F80u : ((w < 0.f) ? 0xBF80u : 0u);
    bt[(size_t)co * KTOT + ks * 32 + (ci ^ (((co >> 1) & 3) << 3))] = s;
}

__global__ __launch_bounds__(NTHREADS, 4)
void bconv_kernel(const __bf16* __restrict__ xb,
                  const unsigned short* __restrict__ bt,
                  const float* __restrict__ bias,
                  float* __restrict__ out,
                  const char* __restrict__ zb) {
    __shared__ __bf16 lds[3 * SLOT_ELEMS];   // 72 KB -> 2 blocks/CU

    const int tid  = threadIdx.x;
    const int lane = tid & 63;
    const int wid  = tid >> 6;

    // XCD-aware bijective swizzle: 784 = 8 * 98
    const int bid = blockIdx.x;
    const int swz = (bid & 7) * (MTOT / BM / 8) + (bid >> 3);
    const int m_base = swz * BM;

    // 8 waves: 2M x 4N, wave tile 64x64
    const int wm = (wid >> 2) * 64;
    const int wn = (wid & 3) * 64;

    // --- B staging: 2 loads/thread; load j: row = j*128 + (tid>>2), chunk tid&3 ---
    // bt pre-swizzled -> conv reads it linearly.
    long bSrc[2];
#pragma unroll
    for (int j = 0; j < 2; ++j) {
        int co = j * 128 + (tid >> 2);
        bSrc[j] = (long)co * (KTOT * 2) + (long)(tid & 3) * 16;
    }

    // --- A staging: 1 load/thread; row = tid>>2, source chunk pre-swizzled:
    //     chunk' = (tid&3) ^ S(row), S(row) = (row>>1)&3 = (tid>>3)&3 ---
    const int schunk = (tid & 3) ^ ((tid >> 3) & 3);
    int aHH, aWW;
    long aBase;
    {
        int r = tid >> 2;                 // 0..127
        int flat = m_base + r;
        aWW = flat % WW;
        aHH = (flat / WW) % HH;
        aBase = (long)flat * (CIN * 2) + schunk * 16;
    }

    f32x4 acc[4][4];
#pragma unroll
    for (int i = 0; i < 4; ++i)
#pragma unroll
        for (int j = 0; j < 4; ++j)
            acc[i][j] = (f32x4){0.f, 0.f, 0.f, 0.f};

    const char* xbb = (const char*)xb;
    const char* btb = (const char*)bt;

    auto STAGE = [&](int ks, int slot) {
        __bf16* As = &lds[slot * SLOT_ELEMS];
        __bf16* Bs = As + BM * BK;
        // B: 2 gload_lds (dest byte = j*8192 + wid*1024 + lane*16, linear in lane)
#pragma unroll
        for (int j = 0; j < 2; ++j)
            gload_lds16(btb + bSrc[j] + (long)ks * 64,
                        &Bs[(j * 128 + wid * 16) * BK]);
        // A: 1 gload_lds, conv gather + boundary zero-page
        const int c2  = ks / 9;
        const int tap = ks - c2 * 9;
        const int dh  = tap / 3 - 1;
        const int dw  = tap % 3 - 1;
        int ih = aHH + dh, iw = aWW + dw;
        bool valid = ((unsigned)ih < (unsigned)HH) && ((unsigned)iw < (unsigned)WW);
        const char* g = valid
            ? (xbb + aBase + (long)(dh * WW + dw) * (CIN * 2) + c2 * 64)
            : (const char*)zb;
        gload_lds16(g, &As[(wid * 16) * BK]);
    };

    // prologue: stage tiles 0,1 into slots 0,1 (6 loads in flight)
    STAGE(0, 0);
    STAGE(1, 1);

    // fragment-read geometry (round-4 proven): row = base + (lane&15),
    // chunk slot = (lane>>4) ^ S(row), S = ((lane&15)>>1)&3
    const int rsel  = lane & 15;
    const int cbyte = ((lane >> 4) ^ ((rsel >> 1) & 3)) * 16;

    int sc = 0;   // slot of current tile t (= t % 3)
    for (int t = 0; t < NSTEPS; ++t) {
        if (t < NSTEPS - 2) {
            const int sp = (sc >= 1) ? (sc - 1) : 2;   // (t+2) % 3
            STAGE(t + 2, sp);
            asm volatile("s_waitcnt vmcnt(6)" ::: "memory");  // tile t landed
        } else if (t == NSTEPS - 2) {
            asm volatile("s_waitcnt vmcnt(3)" ::: "memory");
        } else {
            asm volatile("s_waitcnt vmcnt(0)" ::: "memory");
        }
        __builtin_amdgcn_s_barrier();      // all waves' tile-t staging landed
        asm volatile("" ::: "memory");

        const char* As = (const char*)&lds[sc * SLOT_ELEMS];
        const char* Bs = As + BM * BK * 2;

        bf16x8 af[4], bfr[4];
#pragma unroll
        for (int mi = 0; mi < 4; ++mi)
            af[mi] = *(const bf16x8*)(As + (wm + mi * 16 + rsel) * (BK * 2) + cbyte);
#pragma unroll
        for (int ni = 0; ni < 4; ++ni)
            bfr[ni] = *(const bf16x8*)(Bs + (wn + ni * 16 + rsel) * (BK * 2) + cbyte);

        __builtin_amdgcn_s_setprio(1);
#pragma unroll
        for (int mi = 0; mi < 4; ++mi)
#pragma unroll
            for (int ni = 0; ni < 4; ++ni)
                acc[mi][ni] = __builtin_amdgcn_mfma_f32_16x16x32_bf16(
                    af[mi], bfr[ni], acc[mi][ni], 0, 0, 0);
        __builtin_amdgcn_s_setprio(0);

        asm volatile("s_waitcnt lgkmcnt(0)" ::: "memory");  // my slot-t reads done
        __builtin_amdgcn_s_barrier();      // slot t may be overwritten next iters
        asm volatile("" ::: "memory");

        sc = (sc < 2) ? (sc + 1) : 0;
    }

    // --- epilogue: bias + ReLU.  C/D layout: col = lane&15, row = (lane>>4)*4 + j
    const int col_l  = lane & 15;
    const int row_g4 = (lane >> 4) * 4;
#pragma unroll
    for (int ni = 0; ni < 4; ++ni) {
        const int cout = wn + ni * 16 + col_l;
        const float bv = bias[cout];
#pragma unroll
        for (int mi = 0; mi < 4; ++mi) {
            const int row = m_base + wm + mi * 16 + row_g4;
#pragma unroll
            for (int j = 0; j < 4; ++j) {
                float v = acc[mi][ni][j] + bv;
                out[(size_t)(row + j) * COUT + cout] = v > 0.f ? v : 0.f;
            }
        }
    }
}

// ================= fallback path (ws too small): round-2 fallback, verbatim ====
__global__ void binarize_w_old_kernel(const float* __restrict__ W,
                                      unsigned short* __restrict__ bt) {
    int k  = blockIdx.x;    // tap*256 + cin
    int co = threadIdx.x;
    int tap = k >> 8, cin = k & 255;
    int c = cin >> 6, ci = cin & 63;
    int ks = c * 9 + tap;
    float w = W[(size_t)k * COUT + co];
    unsigned short s = (w > 0.f) ? 0x3F80u : ((w < 0.f) ? 0xBF80u : 0u);
    bt[(size_t)co * KTOT + ks * 64 + (ci ^ ((co & 7) << 3))] = s;
}

__global__ __launch_bounds__(512, 4)
void bconv_old_kernel(const float* __restrict__ x,
                      const unsigned short* __restrict__ bt,
                      const float* __restrict__ bias,
                      float* __restrict__ out) {
    __shared__ __bf16 Al[128][64];
    __shared__ __bf16 Bl[256][64];

    const int tid  = threadIdx.x;
    const int lane = tid & 63;
    const int wid  = tid >> 6;

    const int bid = blockIdx.x;
    const int swz = (bid & 7) * (MTOT / 128 / 8) + (bid >> 3);
    const int m_base = swz * 128;

    const int wm = (wid & 1) * 64;
    const int wn = (wid >> 1) * 64;

    const int  rB0 = wid * 32 + (lane >> 3);
    const long bB0 = (long)rB0 * (KTOT * 2) + (lane & 7) * 16;

    int aH[2], aW[2], aOff[2];
#pragma unroll
    for (int i = 0; i < 2; ++i) {
        int r = i * 64 + (tid >> 3);
        int flat = m_base + r;
        aW[i] = flat % WW;
        aH[i] = (flat / WW) % HH;
        aOff[i] = flat * (CIN * 4);
    }

    f32x4 acc[4][4];
#pragma unroll
    for (int i = 0; i < 4; ++i)
#pragma unroll
        for (int j = 0; j < 4; ++j)
            acc[i][j] = (f32x4){0.f, 0.f, 0.f, 0.f};

    const char* xfb = (const char*)x;
    const char* btb = (const char*)bt;

    for (int ks = 0; ks < 36; ++ks) {
        const int c    = ks / 9;
        const int tap  = ks % 9;
        const int dh   = tap / 3 - 1;
        const int dw   = tap % 3 - 1;
        const int doff = dh * WW + dw;

        __syncthreads();

#pragma unroll
        for (int i = 0; i < 4; ++i) {
            const char* g = btb + bB0 + (long)i * 8 * (KTOT * 2) + ks * 128;
            gload_lds16(g, &Bl[wid * 32 + i * 8][0]);
        }

        const int cg = tid & 7;
#pragma unroll
        for (int i = 0; i < 2; ++i) {
            int ih = aH[i] + dh, iw = aW[i] + dw;
            f32x4 v0 = (f32x4){0.f, 0.f, 0.f, 0.f};
            f32x4 v1 = (f32x4){0.f, 0.f, 0.f, 0.f};
            if (((unsigned)ih < (unsigned)HH) && ((unsigned)iw < (unsigned)WW)) {
                const float* gp = (const float*)(xfb +
                    (long)(aOff[i] + doff * (CIN * 4) + c * 256 + cg * 32));
                v0 = ((const f32x4*)gp)[0];
                v1 = ((const f32x4*)gp)[1];
            }
            bf16x8 o;
            o[0] = (__bf16)v0[0]; o[1] = (__bf16)v0[1];
            o[2] = (__bf16)v0[2]; o[3] = (__bf16)v0[3];
            o[4] = (__bf16)v1[0]; o[5] = (__bf16)v1[1];
            o[6] = (__bf16)v1[2]; o[7] = (__bf16)v1[3];
            int r = i * 64 + (tid >> 3);
            *(bf16x8*)((char*)&Al[0][0] + r * 128 + ((cg * 16) ^ ((r & 7) << 4))) = o;
        }

        __syncthreads();

        const char* Ab = (const char*)&Al[0][0];
        const char* Bb = (const char*)&Bl[0][0];
        const int swzr = (lane & 7) << 4;
        const int rsel = lane & 15;
        const int csel = (lane >> 4) * 16;
#pragma unroll
        for (int kk = 0; kk < 2; ++kk) {
            const int colb = kk * 64 + csel;
            bf16x8 af[4], bfr[4];
#pragma unroll
            for (int mi = 0; mi < 4; ++mi)
                af[mi] = *(const bf16x8*)(Ab + (wm + mi * 16 + rsel) * 128 + (colb ^ swzr));
#pragma unroll
            for (int ni = 0; ni < 4; ++ni)
                bfr[ni] = *(const bf16x8*)(Bb + (wn + ni * 16 + rsel) * 128 + (colb ^ swzr));
#pragma unroll
            for (int mi = 0; mi < 4; ++mi)
#pragma unroll
                for (int ni = 0; ni < 4; ++ni)
                    acc[mi][ni] = __builtin_amdgcn_mfma_f32_16x16x32_bf16(
                        af[mi], bfr[ni], acc[mi][ni], 0, 0, 0);
        }
    }

    const int col_l  = lane & 15;
    const int row_g4 = (lane >> 4) * 4;
#pragma unroll
    for (int ni = 0; ni < 4; ++ni) {
        const int cout = wn + ni * 16 + col_l;
        const float bv = bias[cout];
#pragma unroll
        for (int mi = 0; mi < 4; ++mi) {
            const int row = m_base + wm + mi * 16 + row_g4;
#pragma unroll
            for (int j = 0; j < 4; ++j) {
                float v = acc[mi][ni][j] + bv;
                out[(size_t)(row + j) * COUT + cout] = v > 0.f ? v : 0.f;
            }
        }
    }
}

extern "C" void kernel_launch(void* const* d_in, const int* in_sizes, int n_in,
                              void* d_out, int out_size, void* d_ws, size_t ws_size,
                              hipStream_t stream) {
    const float* x = (const float*)d_in[0];   // (32,56,56,256) fp32
    const float* W = (const float*)d_in[1];   // (3,3,256,256) fp32
    const float* b = (const float*)d_in[2];   // (256,) fp32
    float* out = (float*)d_out;

    char* ws = (char*)d_ws;
    unsigned short* bt = (unsigned short*)ws;
    __bf16* xb   = (__bf16*)(ws + XB_OFF);
    float*  zbuf = (float*)(ws + ZB_OFF);

    if (ws_size >= WS_NEEDED) {
        binarize_w_kernel<<<dim3(KTOT), dim3(COUT), 0, stream>>>(W, bt);
        xcast_kernel<<<dim3(2048), dim3(256), 0, stream>>>(x, xb, zbuf);
        bconv_kernel<<<dim3(MTOT / BM), dim3(NTHREADS), 0, stream>>>(
            xb, bt, b, out, (const char*)zbuf);
    } else {
        binarize_w_old_kernel<<<dim3(KTOT), dim3(COUT), 0, stream>>>(W, bt);
        bconv_old_kernel<<<dim3(MTOT / 128), dim3(512), 0, stream>>>(x, bt, b, out);
    }
}